// Round 6
// baseline (208.731 us; speedup 1.0000x reference)
//
#include <hip/hip_runtime.h>
#include <math.h>

#define NB 8      // NUM_BATCHES
#define C  256    // channels
#define CR 64     // C / r

#define GRID 256  // one block per CU (guaranteed co-resident: LDS > 80 KB)
#define TPB  512  // 8 waves
#define SRG  6    // register-stashed 4-row groups per wave (96 VGPR)
#define SLG  3    // LDS-stashed 4-row groups per wave (96 KB)

typedef float vf4 __attribute__((ext_vector_type(4)));

// tiny init instead of hipMemsetAsync (fill nodes showed ~150us pathology in
// R1/R5 rocprof): zero the two grid-barrier counters every call.
__global__ void init_kernel(int* __restrict__ ctl) { ctl[0] = 0; ctl[1] = 0; }

__device__ __forceinline__ void grid_barrier(int* bar, int target) {
    __syncthreads();
    if (threadIdx.x == 0) {
        __threadfence();                       // release: wb this XCD's L2
        atomicAdd(bar, 1);                     // device-scope
        while (__hip_atomic_load(bar, __ATOMIC_RELAXED,
                                 __HIP_MEMORY_SCOPE_AGENT) < target)
            __builtin_amdgcn_s_sleep(8);
        __threadfence();                       // acquire: inv stale lines
    }
    __syncthreads();
}

__device__ __forceinline__ void load_grp(const float* __restrict__ x,
                                         const int* __restrict__ bids,
                                         size_t r0, int lane,
                                         int& a0, int& a1, int& a2, int& a3,
                                         vf4& v0, vf4& v1, vf4& v2, vf4& v3) {
    a0 = __builtin_amdgcn_readfirstlane(bids[r0 + 0]);
    a1 = __builtin_amdgcn_readfirstlane(bids[r0 + 1]);
    a2 = __builtin_amdgcn_readfirstlane(bids[r0 + 2]);
    a3 = __builtin_amdgcn_readfirstlane(bids[r0 + 3]);
    v0 = __builtin_nontemporal_load(((const vf4*)(x + (r0 + 0) * C)) + lane);
    v1 = __builtin_nontemporal_load(((const vf4*)(x + (r0 + 1) * C)) + lane);
    v2 = __builtin_nontemporal_load(((const vf4*)(x + (r0 + 2) * C)) + lane);
    v3 = __builtin_nontemporal_load(((const vf4*)(x + (r0 + 3) * C)) + lane);
}

__device__ __forceinline__ void accum4(vf4* acc, float* cnt,
                                       int a0, int a1, int a2, int a3,
                                       vf4 v0, vf4 v1, vf4 v2, vf4 v3) {
    #pragma unroll
    for (int b = 0; b < NB; ++b) {
        const float m0 = (a0 == b) ? 1.f : 0.f;
        const float m1 = (a1 == b) ? 1.f : 0.f;
        const float m2 = (a2 == b) ? 1.f : 0.f;
        const float m3 = (a3 == b) ? 1.f : 0.f;
        acc[b] += v0 * m0;
        acc[b] += v1 * m1;
        acc[b] += v2 * m2;
        acc[b] += v3 * m3;
        cnt[b] += m0 + m1 + m2 + m3;
    }
}

__global__ __launch_bounds__(TPB, 2) void fused_kernel(
    const float* __restrict__ x,      // [N, 256]
    const int*   __restrict__ bids,   // [N]
    const float* __restrict__ W1,     // [256][64]
    const float* __restrict__ b1,     // [64]
    const float* __restrict__ W2,     // [64][256]
    const float* __restrict__ b2,     // [256]
    float*       __restrict__ out,    // [N, 256]
    float*       __restrict__ partials, // [GRID][2048]
    float*       __restrict__ cpart,    // [GRID][8]
    float*       __restrict__ gsums,    // [2048]
    float*       __restrict__ gcnts,    // [8]
    int*         __restrict__ ctl,      // [2] barrier counters (init'd to 0)
    int N)
{
    __shared__ vf4   lstash[8 * SLG * 4 * 64];  // 96 KB x-stash
    __shared__ float msum[NB * C];              // 8 KB: merge buf -> pooled -> y
    __shared__ float hbuf[NB * CR];             // 2 KB: reduce scratch -> h
    __shared__ float mcnt[NB];
    __shared__ float cn[NB];

    const int tid  = threadIdx.x;
    const int wid  = tid >> 6;
    const int lane = tid & 63;
    const int blk  = blockIdx.x;

    const int gpw      = N / (GRID * 8 * 4);        // groups per wave (32)
    const int g0       = (blk * 8 + wid) * gpw;     // this wave's first group
    const int mainRows = GRID * 8 * gpw * 4;

    vf4   st[SRG][4];                               // static-index only
    vf4   acc[NB];
    float cnt[NB];
    #pragma unroll
    for (int b = 0; b < NB; ++b) { acc[b] = (vf4){0.f,0.f,0.f,0.f}; cnt[b] = 0.f; }

    // ------------- phase A: pool accumulate (+stash) -------------
    #pragma unroll
    for (int i = 0; i < SRG; ++i) if (i < gpw) {
        int a0, a1, a2, a3; vf4 v0, v1, v2, v3;
        load_grp(x, bids, (size_t)(g0 + i) * 4, lane, a0, a1, a2, a3, v0, v1, v2, v3);
        accum4(acc, cnt, a0, a1, a2, a3, v0, v1, v2, v3);
        st[i][0] = v0; st[i][1] = v1; st[i][2] = v2; st[i][3] = v3;
    }
    #pragma unroll
    for (int i = 0; i < SLG; ++i) if (SRG + i < gpw) {
        int a0, a1, a2, a3; vf4 v0, v1, v2, v3;
        load_grp(x, bids, (size_t)(g0 + SRG + i) * 4, lane, a0, a1, a2, a3, v0, v1, v2, v3);
        accum4(acc, cnt, a0, a1, a2, a3, v0, v1, v2, v3);
        vf4* p = lstash + ((wid * SLG + i) * 4) * 64 + lane;
        p[0] = v0; p[64] = v1; p[128] = v2; p[192] = v3;
    }
    for (int i = SRG + SLG; i < gpw; ++i) {
        int a0, a1, a2, a3; vf4 v0, v1, v2, v3;
        load_grp(x, bids, (size_t)(g0 + i) * 4, lane, a0, a1, a2, a3, v0, v1, v2, v3);
        accum4(acc, cnt, a0, a1, a2, a3, v0, v1, v2, v3);
    }
    if (blk == 0) {                                  // generic-N tail rows
        for (int row = mainRows + wid; row < N; row += 8) {
            const int ab = __builtin_amdgcn_readfirstlane(bids[row]);
            const vf4 v = ((const vf4*)(x + (size_t)row * C))[lane];
            #pragma unroll
            for (int b = 0; b < NB; ++b) {
                const float m = (ab == b) ? 1.f : 0.f;
                acc[b] += v * m; cnt[b] += m;
            }
        }
    }

    // ------------- merge 8 waves through LDS (sequential rounds) -------------
    for (int i = tid; i < NB * C; i += TPB) msum[i] = 0.f;
    if (tid < NB) mcnt[tid] = 0.f;
    __syncthreads();
    for (int w = 0; w < 8; ++w) {
        if (wid == w) {
            #pragma unroll
            for (int b = 0; b < NB; ++b) {
                vf4* p = ((vf4*)(msum + b * C)) + lane;
                *p += acc[b];
            }
            if (lane == 0) {
                #pragma unroll
                for (int b = 0; b < NB; ++b) mcnt[b] += cnt[b];
            }
        }
        __syncthreads();
    }
    for (int i = tid; i < NB * C; i += TPB)
        partials[(size_t)blk * (NB * C) + i] = msum[i];
    if (tid < NB) cpart[blk * NB + tid] = mcnt[tid];

    grid_barrier(&ctl[0], GRID);

    // ------------- phase B: tree-reduce partials (blocks 0..64) -------------
    if (blk < 64) {
        const int c    = blk * 32 + (tid & 31);
        const int rseg = tid >> 5;                  // 0..15
        float s = 0.f;
        for (int r = rseg * 16; r < rseg * 16 + 16; ++r)
            s += partials[(size_t)r * (NB * C) + c];
        hbuf[rseg * 32 + (tid & 31)] = s;
        __syncthreads();
        if (tid < 32) {
            float t = 0.f;
            #pragma unroll
            for (int r = 0; r < 16; ++r) t += hbuf[r * 32 + tid];
            gsums[blk * 32 + tid] = t;
        }
    } else if (blk == 64) {
        if (tid < NB) {
            float t = 0.f;
            for (int p = 0; p < GRID; ++p) t += cpart[p * NB + tid];
            gcnts[tid] = t;
        }
    }

    grid_barrier(&ctl[1], GRID);

    // ------------- phase B2: redundant per-block MLP -> y in msum -------------
    if (tid < NB) cn[tid] = fmaxf(gcnts[tid], 1.f);
    __syncthreads();
    for (int i = tid; i < NB * C; i += TPB)
        msum[i] = gsums[i] / cn[i >> 8];            // pooled
    __syncthreads();
    {
        const int b = tid >> 6, j = tid & 63;       // TPB == NB*CR exactly
        float a = b1[j];
        #pragma unroll 4
        for (int k = 0; k < C; ++k)
            a = fmaf(msum[b * C + k], W1[k * CR + j], a);
        hbuf[tid] = fmaxf(a, 0.f);                  // h
    }
    __syncthreads();
    #pragma unroll
    for (int m = 0; m < (NB * C) / TPB; ++m) {      // 4: y overwrites pooled
        const int o = tid + m * TPB;
        const int b = o >> 8, j = o & 255;
        float a = b2[j];
        #pragma unroll
        for (int k = 0; k < CR; ++k)
            a = fmaf(hbuf[b * CR + k], W2[k * C + j], a);
        msum[o] = 1.f / (1.f + __expf(-a));         // y
    }
    __syncthreads();

    // ------------- phase C: out = y[bid] * x (stash or re-read) -------------
    #pragma unroll
    for (int i = 0; i < SRG; ++i) if (i < gpw) {
        const size_t r0 = (size_t)(g0 + i) * 4;
        const int a0 = __builtin_amdgcn_readfirstlane(bids[r0 + 0]);
        const int a1 = __builtin_amdgcn_readfirstlane(bids[r0 + 1]);
        const int a2 = __builtin_amdgcn_readfirstlane(bids[r0 + 2]);
        const int a3 = __builtin_amdgcn_readfirstlane(bids[r0 + 3]);
        const vf4 y0 = ((const vf4*)(msum + a0 * C))[lane];
        const vf4 y1 = ((const vf4*)(msum + a1 * C))[lane];
        const vf4 y2 = ((const vf4*)(msum + a2 * C))[lane];
        const vf4 y3 = ((const vf4*)(msum + a3 * C))[lane];
        __builtin_nontemporal_store(st[i][0] * y0, ((vf4*)(out + (r0 + 0) * C)) + lane);
        __builtin_nontemporal_store(st[i][1] * y1, ((vf4*)(out + (r0 + 1) * C)) + lane);
        __builtin_nontemporal_store(st[i][2] * y2, ((vf4*)(out + (r0 + 2) * C)) + lane);
        __builtin_nontemporal_store(st[i][3] * y3, ((vf4*)(out + (r0 + 3) * C)) + lane);
    }
    #pragma unroll
    for (int i = 0; i < SLG; ++i) if (SRG + i < gpw) {
        const size_t r0 = (size_t)(g0 + SRG + i) * 4;
        const int a0 = __builtin_amdgcn_readfirstlane(bids[r0 + 0]);
        const int a1 = __builtin_amdgcn_readfirstlane(bids[r0 + 1]);
        const int a2 = __builtin_amdgcn_readfirstlane(bids[r0 + 2]);
        const int a3 = __builtin_amdgcn_readfirstlane(bids[r0 + 3]);
        const vf4* p = lstash + ((wid * SLG + i) * 4) * 64 + lane;
        const vf4 u0 = p[0], u1 = p[64], u2 = p[128], u3 = p[192];
        const vf4 y0 = ((const vf4*)(msum + a0 * C))[lane];
        const vf4 y1 = ((const vf4*)(msum + a1 * C))[lane];
        const vf4 y2 = ((const vf4*)(msum + a2 * C))[lane];
        const vf4 y3 = ((const vf4*)(msum + a3 * C))[lane];
        __builtin_nontemporal_store(u0 * y0, ((vf4*)(out + (r0 + 0) * C)) + lane);
        __builtin_nontemporal_store(u1 * y1, ((vf4*)(out + (r0 + 1) * C)) + lane);
        __builtin_nontemporal_store(u2 * y2, ((vf4*)(out + (r0 + 2) * C)) + lane);
        __builtin_nontemporal_store(u3 * y3, ((vf4*)(out + (r0 + 3) * C)) + lane);
    }
    for (int i = SRG + SLG; i < gpw; ++i) {
        int a0, a1, a2, a3; vf4 v0, v1, v2, v3;
        const size_t r0 = (size_t)(g0 + i) * 4;
        load_grp(x, bids, r0, lane, a0, a1, a2, a3, v0, v1, v2, v3);
        const vf4 y0 = ((const vf4*)(msum + a0 * C))[lane];
        const vf4 y1 = ((const vf4*)(msum + a1 * C))[lane];
        const vf4 y2 = ((const vf4*)(msum + a2 * C))[lane];
        const vf4 y3 = ((const vf4*)(msum + a3 * C))[lane];
        __builtin_nontemporal_store(v0 * y0, ((vf4*)(out + (r0 + 0) * C)) + lane);
        __builtin_nontemporal_store(v1 * y1, ((vf4*)(out + (r0 + 1) * C)) + lane);
        __builtin_nontemporal_store(v2 * y2, ((vf4*)(out + (r0 + 2) * C)) + lane);
        __builtin_nontemporal_store(v3 * y3, ((vf4*)(out + (r0 + 3) * C)) + lane);
    }
    if (blk == 0) {                                  // generic-N tail rows
        for (int row = mainRows + wid; row < N; row += 8) {
            const int ab = __builtin_amdgcn_readfirstlane(bids[row]);
            const vf4 v  = ((const vf4*)(x + (size_t)row * C))[lane];
            const vf4 yv = ((const vf4*)(msum + ab * C))[lane];
            ((vf4*)(out + (size_t)row * C))[lane] = v * yv;
        }
    }
}

extern "C" void kernel_launch(void* const* d_in, const int* in_sizes, int n_in,
                              void* d_out, int out_size, void* d_ws, size_t ws_size,
                              hipStream_t stream)
{
    const float* x    = (const float*)d_in[0];
    const int*   bids = (const int*)  d_in[1];
    const float* W1   = (const float*)d_in[2];
    const float* b1   = (const float*)d_in[3];
    const float* W2   = (const float*)d_in[4];
    const float* b2   = (const float*)d_in[5];
    float* out = (float*)d_out;

    const int N = in_sizes[1];           // 262144

    // ws layout (floats); every region fully written before read each call:
    // partials[256*2048] | cpart[256*8] | gsums[2048] | gcnts[8] | ctl[2]
    float* partials = (float*)d_ws;
    float* cpart    = partials + GRID * (NB * C);
    float* gsums    = cpart + GRID * NB;
    float* gcnts    = gsums + NB * C;
    int*   ctl      = (int*)(gcnts + NB);

    init_kernel <<<1, 1, 0, stream>>>(ctl);
    fused_kernel<<<GRID, TPB, 0, stream>>>(x, bids, W1, b1, W2, b2, out,
                                           partials, cpart, gsums, gcnts, ctl, N);
}

// Round 7
// 169.715 us; speedup vs baseline: 1.2299x; 1.2299x over previous
//
#include <hip/hip_runtime.h>
#include <math.h>

#define NB 8      // NUM_BATCHES
#define C  256    // channels
#define CR 64     // C / r

#define POOL_BLOCKS  1024   // 4 blocks/CU x 4 waves = 16 waves/CU (LDS-capped)
#define SCALE_BLOCKS 2048   // 8 blocks/CU x 4 waves = 32 waves/CU

typedef float vf4 __attribute__((ext_vector_type(4)));

// ---------------------------------------------------------------------------
// Kernel 1: per-batch partial sums + counts. One wave per 4-row group
// (4 KB contiguous NT streaming; one int4 load fetches the 4 bids).
// Wave-uniform bid -> branch-free predicated FMA into vf4 acc[8] (VGPRs).
// LDS merge once at the end; per-block partials out (no atomics, no memset).
// ---------------------------------------------------------------------------
__global__ __launch_bounds__(256) void pool_kernel(
    const float* __restrict__ x,         // [N, 256]
    const int*   __restrict__ bids,      // [N]
    float*       __restrict__ partials,  // [POOL_BLOCKS][2048]
    float*       __restrict__ cpart,     // [POOL_BLOCKS][8]
    int N)
{
    __shared__ float lsum[4][NB][C];   // 32 KB
    __shared__ float lcnt[4][NB];

    const int tid  = threadIdx.x;
    const int wid  = tid >> 6;
    const int lane = tid & 63;

    vf4   acc[NB];
    float cnt[NB];
    #pragma unroll
    for (int b = 0; b < NB; ++b) { acc[b] = (vf4){0.f,0.f,0.f,0.f}; cnt[b] = 0.f; }

    const int gwave   = blockIdx.x * 4 + wid;
    const int totw    = POOL_BLOCKS * 4;
    const int ngroups = N >> 2;

    for (int g = gwave; g < ngroups; g += totw) {
        const size_t r0 = (size_t)g * 4;
        const int4 bb = *((const int4*)(bids + r0));     // 4 bids, 1 load
        const int b0 = __builtin_amdgcn_readfirstlane(bb.x);
        const int b1 = __builtin_amdgcn_readfirstlane(bb.y);
        const int b2 = __builtin_amdgcn_readfirstlane(bb.z);
        const int b3 = __builtin_amdgcn_readfirstlane(bb.w);
        const vf4 v0 = __builtin_nontemporal_load(((const vf4*)(x + (r0 + 0) * C)) + lane);
        const vf4 v1 = __builtin_nontemporal_load(((const vf4*)(x + (r0 + 1) * C)) + lane);
        const vf4 v2 = __builtin_nontemporal_load(((const vf4*)(x + (r0 + 2) * C)) + lane);
        const vf4 v3 = __builtin_nontemporal_load(((const vf4*)(x + (r0 + 3) * C)) + lane);
        #pragma unroll
        for (int b = 0; b < NB; ++b) {
            const float m0 = (b0 == b) ? 1.f : 0.f;
            const float m1 = (b1 == b) ? 1.f : 0.f;
            const float m2 = (b2 == b) ? 1.f : 0.f;
            const float m3 = (b3 == b) ? 1.f : 0.f;
            acc[b] += v0 * m0;
            acc[b] += v1 * m1;
            acc[b] += v2 * m2;
            acc[b] += v3 * m3;
            cnt[b] += m0 + m1 + m2 + m3;
        }
    }
    // leftover rows if N % 4 != 0 (none at N=262144) — wave 0 handles them
    if (gwave == 0) {
        for (int row = ngroups * 4; row < N; ++row) {
            const int bb = __builtin_amdgcn_readfirstlane(bids[row]);
            const vf4 v = ((const vf4*)(x + (size_t)row * C))[lane];
            #pragma unroll
            for (int b = 0; b < NB; ++b) {
                const float m = (bb == b) ? 1.f : 0.f;
                acc[b] += v * m;
                cnt[b] += m;
            }
        }
    }

    // one conflict-free b128 LDS write per batch per lane
    #pragma unroll
    for (int b = 0; b < NB; ++b)
        ((vf4*)&lsum[wid][b][0])[lane] = acc[b];
    if (lane == 0) {
        #pragma unroll
        for (int b = 0; b < NB; ++b) lcnt[wid][b] = cnt[b];
    }
    __syncthreads();

    float* pout = partials + (size_t)blockIdx.x * (NB * C);
    for (int i = tid; i < NB * C; i += 256)
        pout[i] = lsum[0][0][i] + lsum[1][0][i] + lsum[2][0][i] + lsum[3][0][i];
    if (tid < NB)
        cpart[blockIdx.x * NB + tid] =
            lcnt[0][tid] + lcnt[1][tid] + lcnt[2][tid] + lcnt[3][tid];
}

// ---------------------------------------------------------------------------
// Kernel 2: tree-reduce the per-block partials. 64 blocks: blockIdx = jp*8+jo;
// block sums PR partial rows over its 256-col chunk (coalesced 1 KB reads).
// jo==0 blocks also reduce the count partials.
// ---------------------------------------------------------------------------
__global__ __launch_bounds__(256) void reduce_kernel(
    const float* __restrict__ partials,  // [POOL_BLOCKS][2048]
    const float* __restrict__ cpart,     // [POOL_BLOCKS][8]
    float*       __restrict__ partial2,  // [8][2048]
    float*       __restrict__ c2)        // [8][8]
{
    const int jo  = blockIdx.x & 7;   // column chunk
    const int jp  = blockIdx.x >> 3;  // partial-row chunk
    const int col = jo * 256 + threadIdx.x;
    const int PR  = POOL_BLOCKS / 8;  // 128 rows per jp

    float s = 0.f;
    #pragma unroll 8
    for (int p = 0; p < PR; ++p)
        s += partials[(size_t)(jp * PR + p) * (NB * C) + col];
    partial2[jp * (NB * C) + col] = s;

    if (jo == 0 && threadIdx.x < NB) {
        float c = 0.f;
        for (int p = 0; p < PR; ++p)
            c += cpart[(jp * PR + p) * NB + threadIdx.x];
        c2[jp * NB + threadIdx.x] = c;
    }
}

// ---------------------------------------------------------------------------
// Kernel 3: final reduce + tiny MLP. pooled = sums/max(cnt,1);
// h = relu(pooled@W1+b1); y = sigmoid(h@W2+b2). One block, 256 threads.
// ---------------------------------------------------------------------------
__global__ __launch_bounds__(256) void mlp_kernel(
    const float* __restrict__ partial2,  // [8][2048]
    const float* __restrict__ c2,        // [8][8]
    const float* __restrict__ W1,        // [256][64]
    const float* __restrict__ b1,        // [64]
    const float* __restrict__ W2,        // [64][256]
    const float* __restrict__ b2,        // [256]
    float*       __restrict__ y)         // [8][256] out
{
    __shared__ float pooled[NB][C];
    __shared__ float h[NB][CR];
    __shared__ float cnts[NB];
    const int tid = threadIdx.x;

    if (tid < NB) {
        float c = 0.f;
        #pragma unroll
        for (int j = 0; j < 8; ++j) c += c2[j * NB + tid];
        cnts[tid] = fmaxf(c, 1.f);
    }
    __syncthreads();

    for (int i = tid; i < NB * C; i += 256) {
        float s = 0.f;
        #pragma unroll
        for (int j = 0; j < 8; ++j) s += partial2[j * (NB * C) + i];
        (&pooled[0][0])[i] = s / cnts[i >> 8];
    }
    __syncthreads();

    // h: 8*64 = 512 outputs, 2 per thread
    for (int o = tid; o < NB * CR; o += 256) {
        const int b = o >> 6, j = o & 63;
        float acc = b1[j];
        #pragma unroll 4
        for (int k = 0; k < C; ++k) acc = fmaf(pooled[b][k], W1[k * CR + j], acc);
        (&h[0][0])[o] = fmaxf(acc, 0.f);
    }
    __syncthreads();

    // y: 8*256 = 2048 outputs, 8 per thread
    for (int o = tid; o < NB * C; o += 256) {
        const int b = o >> 8, j = o & 255;
        float acc = b2[j];
        #pragma unroll
        for (int k = 0; k < CR; ++k) acc = fmaf(h[b][k], W2[k * C + j], acc);
        y[o] = 1.f / (1.f + __expf(-acc));
    }
}

// ---------------------------------------------------------------------------
// Kernel 4: out[row,:] = y[bids[row],:] * x[row,:]. One wave per 4-row group
// (4 KB contiguous read + 4 KB write), FORWARD order, y cached in LDS
// (uniform bid -> 2-way b128 = free), NT load/store, int4 bids load.
// ---------------------------------------------------------------------------
__global__ __launch_bounds__(256) void scale_kernel(
    const float* __restrict__ x,     // [N, 256]
    const int*   __restrict__ bids,  // [N]
    const float* __restrict__ y,     // [8][256]
    float*       __restrict__ out,   // [N, 256]
    int N)
{
    __shared__ float ly[NB][C];      // 8 KB
    const int tid = threadIdx.x;
    for (int i = tid; i < NB * C; i += 256) (&ly[0][0])[i] = y[i];
    __syncthreads();

    const int wid  = tid >> 6;
    const int lane = tid & 63;
    const int gwave   = blockIdx.x * 4 + wid;
    const int totw    = SCALE_BLOCKS * 4;
    const int ngroups = N >> 2;

    for (int g = gwave; g < ngroups; g += totw) {
        const size_t r0 = (size_t)g * 4;
        const int4 bb = *((const int4*)(bids + r0));     // 4 bids, 1 load
        const int b0 = __builtin_amdgcn_readfirstlane(bb.x);
        const int b1 = __builtin_amdgcn_readfirstlane(bb.y);
        const int b2 = __builtin_amdgcn_readfirstlane(bb.z);
        const int b3 = __builtin_amdgcn_readfirstlane(bb.w);
        const vf4 v0 = __builtin_nontemporal_load(((const vf4*)(x + (r0 + 0) * C)) + lane);
        const vf4 v1 = __builtin_nontemporal_load(((const vf4*)(x + (r0 + 1) * C)) + lane);
        const vf4 v2 = __builtin_nontemporal_load(((const vf4*)(x + (r0 + 2) * C)) + lane);
        const vf4 v3 = __builtin_nontemporal_load(((const vf4*)(x + (r0 + 3) * C)) + lane);
        const vf4 g0 = ((const vf4*)&ly[b0][0])[lane];
        const vf4 g1 = ((const vf4*)&ly[b1][0])[lane];
        const vf4 g2 = ((const vf4*)&ly[b2][0])[lane];
        const vf4 g3 = ((const vf4*)&ly[b3][0])[lane];
        __builtin_nontemporal_store(v0 * g0, ((vf4*)(out + (r0 + 0) * C)) + lane);
        __builtin_nontemporal_store(v1 * g1, ((vf4*)(out + (r0 + 1) * C)) + lane);
        __builtin_nontemporal_store(v2 * g2, ((vf4*)(out + (r0 + 2) * C)) + lane);
        __builtin_nontemporal_store(v3 * g3, ((vf4*)(out + (r0 + 3) * C)) + lane);
    }
    if (gwave == 0) {
        for (int row = ngroups * 4; row < N; ++row) {
            const int bb = __builtin_amdgcn_readfirstlane(bids[row]);
            const vf4 v  = ((const vf4*)(x + (size_t)row * C))[lane];
            const vf4 gg = ((const vf4*)&ly[bb][0])[lane];
            ((vf4*)(out + (size_t)row * C))[lane] = v * gg;
        }
    }
}

extern "C" void kernel_launch(void* const* d_in, const int* in_sizes, int n_in,
                              void* d_out, int out_size, void* d_ws, size_t ws_size,
                              hipStream_t stream)
{
    const float* x    = (const float*)d_in[0];
    const int*   bids = (const int*)  d_in[1];
    const float* W1   = (const float*)d_in[2];
    const float* b1   = (const float*)d_in[3];
    const float* W2   = (const float*)d_in[4];
    const float* b2   = (const float*)d_in[5];
    float* out = (float*)d_out;

    const int N = in_sizes[1];           // 262144

    // ws layout (floats), all regions fully written before read each call:
    // partials[1024*2048] | cpart[1024*8] | partial2[8*2048] | c2[64] | gy[2048]
    float* partials = (float*)d_ws;
    float* cpart    = partials + POOL_BLOCKS * (NB * C);
    float* partial2 = cpart + POOL_BLOCKS * NB;
    float* c2       = partial2 + 8 * (NB * C);
    float* gy       = c2 + 64;

    pool_kernel  <<<POOL_BLOCKS, 256, 0, stream>>>(x, bids, partials, cpart, N);
    reduce_kernel<<<64, 256, 0, stream>>>(partials, cpart, partial2, c2);
    mlp_kernel   <<<1, 256, 0, stream>>>(partial2, c2, W1, b1, W2, b2, gy);
    scale_kernel <<<SCALE_BLOCKS, 256, 0, stream>>>(x, bids, gy, out, N);
}